// Round 2
// baseline (2945.465 us; speedup 1.0000x reference)
//
#include <hip/hip_runtime.h>
#include <hip/hip_bf16.h>

// GRU-scan model, MI355X. R1 strategy:
//  k1_prep : cvt weights to bf16, fold biases, init h/acc buffers (in ws)
//  k2_xi   : xi[t][b][3H] = x@W_ih^T + (b_ih + b_hh_{r,z} fold)   (bf16, tiled MFMA)
//  k2_tio  : tio[t][b][O] = silu(x@Wt^T + bt)@Wo^T + bo           (bf16, fused 2-stage)
//  k3_rec  : persistent recurrence. 512 thr / 8 waves, W_hh split 8 ways ->
//            192 VGPR/wave (truly resident, 2 waves/SIMD). Batch rows at
//            M-rows {0,4,8,12} -> gating in-register, 1 barrier/step.
//            Streams h_t to ws for k5. No proj in the serial loop.
//  k5_out  : (h_t@Wo^T + tio)*sig(h_t@Wg^T+bg) mean-accum, barrier-free GEMM.
//  k4_out  : out = acc / 512

typedef __attribute__((ext_vector_type(8))) __bf16 bf16x8;
typedef __attribute__((ext_vector_type(4))) __bf16 bf16x4;
typedef __attribute__((ext_vector_type(4))) float f32x4;

#define MFMA(a, b, c) __builtin_amdgcn_mfma_f32_16x16x32_bf16(a, b, c, 0, 0, 0)

__device__ __forceinline__ float fsig(float v) {
  float e = __builtin_amdgcn_exp2f(v * -1.442695041f);
  return __builtin_amdgcn_rcpf(1.0f + e);
}
__device__ __forceinline__ float ftanh(float v) {
  float e = __builtin_amdgcn_exp2f(v * 2.885390082f);
  return 1.0f - 2.0f * __builtin_amdgcn_rcpf(1.0f + e);
}

// ---- workspace layout (bytes) ----
#define O_WIN 0u         // [1024][128] bf16  (W_ih rows 0-767, Wt rows 768-1023)
#define O_WHH 262144u    // [768][256] bf16
#define O_WO  655360u    // [64][256] bf16
#define O_WG  688128u    // [64][256] bf16
#define O_B1  720896u    // [1024] f32 folded bias
#define O_H   724992u    // [1024][256] f32 h state
#define O_ACC 1773568u   // [1024][64] f32 output accumulator
#define O_TIO 2035712u   // [TC][1024][64] bf16, then hhist [TC][1024][256] bf16,
                         // then xi [TC][1024][768] bf16

__global__ void k1_prep(const float* __restrict__ Wih, const float* __restrict__ Wt,
                        const float* __restrict__ Whh, const float* __restrict__ Wo,
                        const float* __restrict__ Wg, const float* __restrict__ bih,
                        const float* __restrict__ bhh, const float* __restrict__ bt,
                        const float* __restrict__ h0, char* __restrict__ ws) {
  unsigned n = blockIdx.x * 256u + threadIdx.x;
  __bf16* win = (__bf16*)(ws + O_WIN);
  __bf16* whh = (__bf16*)(ws + O_WHH);
  __bf16* wo = (__bf16*)(ws + O_WO);
  __bf16* wg = (__bf16*)(ws + O_WG);
  float* b1 = (float*)(ws + O_B1);
  float* hb = (float*)(ws + O_H);
  float* ac = (float*)(ws + O_ACC);
  if (n < 98304u) win[n] = (__bf16)Wih[n];
  else if (n < 131072u) { unsigned i = n - 98304u; win[98304u + i] = (__bf16)Wt[i]; }
  else if (n < 327680u) { unsigned i = n - 131072u; whh[i] = (__bf16)Whh[i]; }
  else if (n < 344064u) { unsigned i = n - 327680u; wo[i] = (__bf16)Wo[i]; }
  else if (n < 360448u) { unsigned i = n - 344064u; wg[i] = (__bf16)Wg[i]; }
  else if (n < 361472u) {
    unsigned i = n - 360448u;
    float v = (i < 512u) ? (bih[i] + bhh[i]) : ((i < 768u) ? bih[i] : bt[i - 768u]);
    b1[i] = v;
  } else if (n < 623616u) { unsigned i = n - 361472u; hb[i] = h0[i]; }
  else if (n < 689152u) { unsigned i = n - 623616u; ac[i] = 0.0f; }
}

// ---------------- k2_xi: xi = x @ W_ih^T + bias1 (cols 0..767) ----------------
__global__ __launch_bounds__(256, 2) void k2_xi(
    const float* __restrict__ x, const __bf16* __restrict__ win,
    const float* __restrict__ b1, __bf16* __restrict__ xi, int t0, int tcbits) {
  extern __shared__ char sm2[];
  __bf16* Asm = (__bf16*)sm2;            // [128][136]
  __bf16* Bsm = (__bf16*)(sm2 + 34816);  // [128][136]
  const int tid = threadIdx.x;
  const int lane = tid & 63, wv = tid >> 6;
  const int m0 = blockIdx.x * 128;
  const int tcm = (1 << tcbits) - 1;
#pragma unroll
  for (int rnd = 0; rnd < 16; ++rnd) {
    int row = rnd * 8 + (tid >> 5);
    int cr = m0 + row;
    int bb = cr >> tcbits, tt = cr & tcm;
    const float* xr = x + ((size_t)bb * 512 + (size_t)(t0 + tt)) * 128 + (tid & 31) * 4;
    float4 v = *(const float4*)xr;
    bf16x4 b4 = {(__bf16)v.x, (__bf16)v.y, (__bf16)v.z, (__bf16)v.w};
    *(bf16x4*)&Asm[row * 136 + (tid & 31) * 4] = b4;
  }
  for (int nc = 0; nc < 6; ++nc) {
    __syncthreads();
#pragma unroll
    for (int rnd = 0; rnd < 8; ++rnd) {
      int rr = rnd * 16 + (tid >> 4);
      uint4 w4 = *(const uint4*)(win + (size_t)(nc * 128 + rr) * 128 + (tid & 15) * 8);
      *(uint4*)&Bsm[rr * 136 + (tid & 15) * 8] = w4;
    }
    __syncthreads();
    f32x4 zv = {0.f, 0.f, 0.f, 0.f};
    f32x4 acc[2][8];
#pragma unroll
    for (int mi = 0; mi < 2; ++mi)
#pragma unroll
      for (int nt = 0; nt < 8; ++nt) acc[mi][nt] = zv;
#pragma unroll
    for (int kt = 0; kt < 4; ++kt) {
      bf16x8 a0 = *(const bf16x8*)&Asm[(wv * 32 + (lane & 15)) * 136 + kt * 32 + (lane >> 4) * 8];
      bf16x8 a1 = *(const bf16x8*)&Asm[(wv * 32 + 16 + (lane & 15)) * 136 + kt * 32 + (lane >> 4) * 8];
#pragma unroll
      for (int nt = 0; nt < 8; ++nt) {
        bf16x8 b = *(const bf16x8*)&Bsm[(nt * 16 + (lane & 15)) * 136 + kt * 32 + (lane >> 4) * 8];
        acc[0][nt] = MFMA(a0, b, acc[0][nt]);
        acc[1][nt] = MFMA(a1, b, acc[1][nt]);
      }
    }
    __syncthreads();
#pragma unroll
    for (int nt = 0; nt < 8; ++nt) {
      float bv = b1[nc * 128 + nt * 16 + (lane & 15)];
#pragma unroll
      for (int mi = 0; mi < 2; ++mi)
#pragma unroll
        for (int r = 0; r < 4; ++r) {
          int rowb = wv * 32 + mi * 16 + (lane >> 4) * 4 + r;
          Bsm[rowb * 136 + nt * 16 + (lane & 15)] = (__bf16)(acc[mi][nt][r] + bv);
        }
    }
    __syncthreads();
#pragma unroll
    for (int rnd = 0; rnd < 8; ++rnd) {
      int row = rnd * 16 + (tid >> 4);
      int cr = m0 + row;
      int bb = cr >> tcbits, tt = cr & tcm;
      uint4 v = *(const uint4*)&Bsm[row * 136 + (tid & 15) * 8];
      *(uint4*)(xi + ((size_t)tt * 1024 + bb) * 768 + nc * 128 + (tid & 15) * 8) = v;
    }
  }
}

// -------- k2_tio: tio = silu(x@Wt^T + bt) @ Wo^T + bo --------
__global__ __launch_bounds__(256, 1) void k2_tio(
    const float* __restrict__ x, const __bf16* __restrict__ win,
    const __bf16* __restrict__ wo, const float* __restrict__ b1,
    const float* __restrict__ bo, __bf16* __restrict__ tio, int t0, int tcbits) {
  extern __shared__ char sm3[];
  __bf16* Asm = (__bf16*)sm3;             // [128][136]
  __bf16* Bsm = (__bf16*)(sm3 + 34816);   // [128][136] then [64][264]
  __bf16* Ti = (__bf16*)(sm3 + 69632);    // [128][264]
  const int tid = threadIdx.x;
  const int lane = tid & 63, wv = tid >> 6;
  const int m0 = blockIdx.x * 128;
  const int tcm = (1 << tcbits) - 1;
#pragma unroll
  for (int rnd = 0; rnd < 16; ++rnd) {
    int row = rnd * 8 + (tid >> 5);
    int cr = m0 + row;
    int bb = cr >> tcbits, tt = cr & tcm;
    const float* xr = x + ((size_t)bb * 512 + (size_t)(t0 + tt)) * 128 + (tid & 31) * 4;
    float4 v = *(const float4*)xr;
    bf16x4 b4 = {(__bf16)v.x, (__bf16)v.y, (__bf16)v.z, (__bf16)v.w};
    *(bf16x4*)&Asm[row * 136 + (tid & 31) * 4] = b4;
  }
  for (int nc = 0; nc < 2; ++nc) {
    __syncthreads();
#pragma unroll
    for (int rnd = 0; rnd < 8; ++rnd) {
      int rr = rnd * 16 + (tid >> 4);
      uint4 w4 = *(const uint4*)(win + (size_t)(98304 / 128 + nc * 128 + rr) * 128 + (tid & 15) * 8);
      *(uint4*)&Bsm[rr * 136 + (tid & 15) * 8] = w4;
    }
    __syncthreads();
    f32x4 zv = {0.f, 0.f, 0.f, 0.f};
    f32x4 acc[2][8];
#pragma unroll
    for (int mi = 0; mi < 2; ++mi)
#pragma unroll
      for (int nt = 0; nt < 8; ++nt) acc[mi][nt] = zv;
#pragma unroll
    for (int kt = 0; kt < 4; ++kt) {
      bf16x8 a0 = *(const bf16x8*)&Asm[(wv * 32 + (lane & 15)) * 136 + kt * 32 + (lane >> 4) * 8];
      bf16x8 a1 = *(const bf16x8*)&Asm[(wv * 32 + 16 + (lane & 15)) * 136 + kt * 32 + (lane >> 4) * 8];
#pragma unroll
      for (int nt = 0; nt < 8; ++nt) {
        bf16x8 b = *(const bf16x8*)&Bsm[(nt * 16 + (lane & 15)) * 136 + kt * 32 + (lane >> 4) * 8];
        acc[0][nt] = MFMA(a0, b, acc[0][nt]);
        acc[1][nt] = MFMA(a1, b, acc[1][nt]);
      }
    }
#pragma unroll
    for (int nt = 0; nt < 8; ++nt) {
      float bv = b1[768 + nc * 128 + nt * 16 + (lane & 15)];
#pragma unroll
      for (int mi = 0; mi < 2; ++mi)
#pragma unroll
        for (int r = 0; r < 4; ++r) {
          int rowb = wv * 32 + mi * 16 + (lane >> 4) * 4 + r;
          float s = acc[mi][nt][r] + bv;
          s = s * __builtin_amdgcn_rcpf(1.0f + __builtin_amdgcn_exp2f(s * -1.442695041f));
          Ti[rowb * 264 + nc * 128 + nt * 16 + (lane & 15)] = (__bf16)s;
        }
    }
  }
  __syncthreads();
  for (int i = tid; i < 2048; i += 256) {
    int row = i >> 5;
    int c8 = (i & 31) * 8;
    *(uint4*)&Bsm[row * 264 + c8] = *(const uint4*)(wo + row * 256 + c8);
  }
  __syncthreads();
  f32x4 zv = {0.f, 0.f, 0.f, 0.f};
  f32x4 acc2[2][4];
#pragma unroll
  for (int mi = 0; mi < 2; ++mi)
#pragma unroll
    for (int nt = 0; nt < 4; ++nt) acc2[mi][nt] = zv;
#pragma unroll
  for (int kt = 0; kt < 8; ++kt) {
    bf16x8 a0 = *(const bf16x8*)&Ti[(wv * 32 + (lane & 15)) * 264 + kt * 32 + (lane >> 4) * 8];
    bf16x8 a1 = *(const bf16x8*)&Ti[(wv * 32 + 16 + (lane & 15)) * 264 + kt * 32 + (lane >> 4) * 8];
#pragma unroll
    for (int nt = 0; nt < 4; ++nt) {
      bf16x8 b = *(const bf16x8*)&Bsm[(nt * 16 + (lane & 15)) * 264 + kt * 32 + (lane >> 4) * 8];
      acc2[0][nt] = MFMA(a0, b, acc2[0][nt]);
      acc2[1][nt] = MFMA(a1, b, acc2[1][nt]);
    }
  }
#pragma unroll
  for (int nt = 0; nt < 4; ++nt) {
    int col = nt * 16 + (lane & 15);
    float bv = bo[col];
#pragma unroll
    for (int mi = 0; mi < 2; ++mi)
#pragma unroll
      for (int r = 0; r < 4; ++r) {
        int rowb = wv * 32 + mi * 16 + (lane >> 4) * 4 + r;
        int cr = m0 + rowb;
        int bb = cr >> tcbits, tt = cr & tcm;
        tio[((size_t)tt * 1024 + bb) * 64 + col] = (__bf16)(acc2[mi][nt][r] + bv);
      }
  }
}

// ---------------- k3_rec: persistent GRU recurrence ----------------
// 256 blocks x 512 thr (8 waves, 2/SIMD). Block owns batch rows b0..b0+3,
// placed at MFMA M-rows {0,4,8,12} so C reg 0 = (row=lane>>4, col=lane&15).
// Wave w owns h-cols [32w,32w+32): wf[2 coltiles][3 gates][8 kt] = 192 VGPR.
// One barrier per step. h_t streamed to hhist for k5.
__global__ __launch_bounds__(512, 2) void k3_rec(
    const __bf16* __restrict__ xi, const __bf16* __restrict__ whh,
    const float* __restrict__ bhn, float* __restrict__ hbuf,
    __bf16* __restrict__ hhist, int TC) {
  __shared__ __bf16 h_lds[2][4224];  // [2][16][264], rows {0,4,8,12} live
  const int tid = threadIdx.x;
  const int lane = tid & 63, w = tid >> 6;
  const int ln = lane & 15, kg = lane >> 4;  // kg = C-row group / B-k group
  const int b0 = blockIdx.x * 4;

  // register-resident W_hh fragments: [c][g][kt]
  bf16x8 wf[2][3][8];
#pragma unroll
  for (int c = 0; c < 2; ++c)
#pragma unroll
    for (int g = 0; g < 3; ++g)
#pragma unroll
      for (int kt = 0; kt < 8; ++kt) {
        int rowg = g * 256 + w * 32 + c * 16 + ln;
        wf[c][g][kt] = *(const bf16x8*)(whh + (size_t)rowg * 256 + kt * 32 + kg * 8);
      }
  // zero both h buffers
  for (int i = tid; i < 4224; i += 512) ((unsigned*)h_lds)[i] = 0u;
  __syncthreads();
  // init h master (fp32) + bf16 copy in h_lds[0] at rows 4*kg
  float hm[2], bhnv[2];
#pragma unroll
  for (int c = 0; c < 2; ++c) {
    int col = w * 32 + c * 16 + ln;
    hm[c] = hbuf[(size_t)(b0 + kg) * 256 + col];
    h_lds[0][(4 * kg) * 264 + col] = (__bf16)hm[c];
    bhnv[c] = bhn[col];
  }
  __syncthreads();

  const int voff = (b0 + kg) * 768 + w * 32 + ln;  // per-lane xi elem offset

#pragma unroll 1
  for (int t = 0; t < TC; ++t) {
    const int cur = t & 1, nxt = cur ^ 1;
    // prefetch this step's xi gate values (6 scalars/lane; consumed pre-barrier)
    const __bf16* xt = xi + (size_t)t * 786432 + voff;
    __bf16 pf[2][3];
#pragma unroll
    for (int c = 0; c < 2; ++c)
#pragma unroll
      for (int g = 0; g < 3; ++g) pf[c][g] = xt[g * 256 + c * 16];
    // hh + gating, per col-tile c (keeps acc pressure at 12 regs)
#pragma unroll
    for (int c = 0; c < 2; ++c) {
      f32x4 ar = {0.f, 0.f, 0.f, 0.f};
      f32x4 az = {0.f, 0.f, 0.f, 0.f};
      f32x4 an = {0.f, 0.f, 0.f, 0.f};
#pragma unroll
      for (int kt = 0; kt < 8; ++kt) {
        bf16x8 a = *(const bf16x8*)&h_lds[cur][ln * 264 + kt * 32 + kg * 8];
        ar = MFMA(a, wf[c][0][kt], ar);
        az = MFMA(a, wf[c][1][kt], az);
        an = MFMA(a, wf[c][2][kt], an);
      }
      float r = fsig((float)pf[c][0] + ar[0]);
      float z = fsig((float)pf[c][1] + az[0]);
      float n = ftanh((float)pf[c][2] + r * (an[0] + bhnv[c]));
      hm[c] = n + z * (hm[c] - n);
      h_lds[nxt][(4 * kg) * 264 + w * 32 + c * 16 + ln] = (__bf16)hm[c];
    }
    __syncthreads();  // h_new visible
    // stream h_t to hhist (coalesced via LDS)
    {
      int row = tid >> 7, cd = tid & 127;
      unsigned v = *(const unsigned*)&h_lds[nxt][(4 * row) * 264 + cd * 2];
      *(unsigned*)(hhist + ((size_t)t * 1024 + b0 + row) * 256 + cd * 2) = v;
    }
  }
  // writeback fp32 state
#pragma unroll
  for (int c = 0; c < 2; ++c)
    hbuf[(size_t)(b0 + kg) * 256 + w * 32 + c * 16 + ln] = hm[c];
}

// ---------------- k5_out: out-proj over stored h, barrier-free ----------------
// grid = 8 btiles x (TC/16) tchunks; block 256 thr / 4 waves.
// Wave w: out-cols [16w,16w+16) for both Wo and Wg (B-frags resident, 64 VGPR).
__global__ __launch_bounds__(256, 3) void k5_out(
    const __bf16* __restrict__ hhist, const __bf16* __restrict__ tio,
    const __bf16* __restrict__ wo, const __bf16* __restrict__ wg,
    const float* __restrict__ bg, float* __restrict__ accb, int TC) {
  const int tid = threadIdx.x;
  const int lane = tid & 63, w = tid >> 6;
  const int ln = lane & 15, kg = lane >> 4;
  const int bt = blockIdx.x & 7;
  const int t0 = (blockIdx.x >> 3) * 16;
  bf16x8 bfo[8], bfg[8];
#pragma unroll
  for (int kt = 0; kt < 8; ++kt) {
    bfo[kt] = *(const bf16x8*)(wo + (size_t)(w * 16 + ln) * 256 + kt * 32 + kg * 8);
    bfg[kt] = *(const bf16x8*)(wg + (size_t)(w * 16 + ln) * 256 + kt * 32 + kg * 8);
  }
  float bgv = bg[w * 16 + ln];
  f32x4 oacc[8];
#pragma unroll
  for (int m = 0; m < 8; ++m) oacc[m] = (f32x4){0.f, 0.f, 0.f, 0.f};
#pragma unroll 1
  for (int tt = 0; tt < 16; ++tt) {
    int t = t0 + tt;
    if (t >= TC) break;
    const __bf16* hrow = hhist + ((size_t)t * 1024 + bt * 128) * 256;
    const __bf16* trow = tio + ((size_t)t * 1024 + bt * 128) * 64;
#pragma unroll
    for (int m = 0; m < 8; ++m) {
      f32x4 po = {0.f, 0.f, 0.f, 0.f};
      f32x4 pg = {0.f, 0.f, 0.f, 0.f};
#pragma unroll
      for (int kt = 0; kt < 8; ++kt) {
        bf16x8 a = *(const bf16x8*)(hrow + (size_t)(m * 16 + ln) * 256 + kt * 32 + kg * 8);
        po = MFMA(a, bfo[kt], po);
        pg = MFMA(a, bfg[kt], pg);
      }
#pragma unroll
      for (int r = 0; r < 4; ++r) {
        int row = m * 16 + kg * 4 + r;
        float tv = (float)trow[row * 64 + w * 16 + ln];
        oacc[m][r] += (po[r] + tv) * fsig(pg[r] + bgv);
      }
    }
  }
#pragma unroll
  for (int m = 0; m < 8; ++m)
#pragma unroll
    for (int r = 0; r < 4; ++r)
      atomicAdd(&accb[(size_t)(bt * 128 + m * 16 + kg * 4 + r) * 64 + w * 16 + ln],
                oacc[m][r]);
}

__global__ void k4_out(const float* __restrict__ accb, float* __restrict__ out) {
  int i = blockIdx.x * 256 + threadIdx.x;
  out[i] = accb[i] * (1.0f / 512.0f);
}

extern "C" void kernel_launch(void* const* d_in, const int* in_sizes, int n_in,
                              void* d_out, int out_size, void* d_ws, size_t ws_size,
                              hipStream_t stream) {
  const float* x = (const float*)d_in[0];
  const float* h0 = (const float*)d_in[1];
  const float* Wih = (const float*)d_in[2];
  const float* bih = (const float*)d_in[3];
  const float* Whh = (const float*)d_in[4];
  const float* bhh = (const float*)d_in[5];
  const float* Wt = (const float*)d_in[6];
  const float* bt = (const float*)d_in[7];
  const float* Wo = (const float*)d_in[8];
  const float* bo = (const float*)d_in[9];
  const float* Wg = (const float*)d_in[10];
  const float* bg = (const float*)d_in[11];
  float* out = (float*)d_out;
  char* ws = (char*)d_ws;

  // per-t bytes: tio 131072 + hhist 524288 + xi 1572864 = 2228224
  int TC = 512;
  while (TC > 1 && (2035712ull + (size_t)TC * 2228224ull) > ws_size) TC >>= 1;
  int tcbits = 0;
  while ((1 << tcbits) != TC) ++tcbits;

  __bf16* win = (__bf16*)(ws + O_WIN);
  __bf16* whhb = (__bf16*)(ws + O_WHH);
  __bf16* wob = (__bf16*)(ws + O_WO);
  __bf16* wgb = (__bf16*)(ws + O_WG);
  float* b1 = (float*)(ws + O_B1);
  float* hbuf = (float*)(ws + O_H);
  float* accb = (float*)(ws + O_ACC);
  __bf16* tioc = (__bf16*)(ws + O_TIO);
  __bf16* hhist = (__bf16*)(ws + O_TIO + (size_t)TC * 131072u);
  __bf16* xic = (__bf16*)(ws + O_TIO + (size_t)TC * 655360u);

  (void)hipFuncSetAttribute((const void*)k2_xi, hipFuncAttributeMaxDynamicSharedMemorySize, 69632);
  (void)hipFuncSetAttribute((const void*)k2_tio, hipFuncAttributeMaxDynamicSharedMemorySize, 137216);

  k1_prep<<<2692, 256, 0, stream>>>(Wih, Wt, Whh, Wo, Wg, bih, bhh, bt, h0, ws);
  int nch = 512 / TC;
  for (int c = 0; c < nch; ++c) {
    int t0 = c * TC;
    k2_xi<<<8 * TC, 256, 69632, stream>>>(x, win, b1, xic, t0, tcbits);
    k2_tio<<<8 * TC, 256, 137216, stream>>>(x, win, wob, b1, bo, tioc, t0, tcbits);
    k3_rec<<<256, 512, 0, stream>>>(xic, whhb, bhh + 512, hbuf, hhist, TC);
    int tch = (TC + 15) >> 4;
    k5_out<<<8 * tch, 256, 0, stream>>>(hhist, tioc, wob, wgb, bg, accb, TC);
  }
  k4_out<<<256, 256, 0, stream>>>(accb, out);
}